// Round 5
// baseline (853.919 us; speedup 1.0000x reference)
//
#include <hip/hip_runtime.h>
#include <math.h>

// ---- problem constants (static per reference) ----
#define D_MODEL   256
#define N_HEADS   8
#define HEAD_DIM  32
#define N_LEVELS  3
#define N_POINTS  2
#define BS        16
#define NQ        900
#define LEN_IN    13125
#define M_Q       (BS * NQ * N_LEVELS)   // 43200
#define M_V       (BS * LEN_IN)          // 210000
#define NCAT      144                    // 96 offset cols + 48 attn cols
#define NCATP     192                    // padded to 3 wave-col-groups of 64

typedef _Float16 f16x8 __attribute__((ext_vector_type(8)));
typedef _Float16 f16x4 __attribute__((ext_vector_type(4)));
typedef float f32x4 __attribute__((ext_vector_type(4)));

// ---------------------------------------------------------------------------
// Weight prep: W[K=256][N] fp32 -> Wt_hi[n][k], Wt_lo[n][k] fp16 split.
// ---------------------------------------------------------------------------
__global__ __launch_bounds__(256) void convert_weight_kernel(
    const float* __restrict__ W, _Float16* __restrict__ Wth,
    _Float16* __restrict__ Wtl, int N, int Npad) {
  const int idx = blockIdx.x * 256 + threadIdx.x;
  if (idx >= Npad * 256) return;
  const int n = idx >> 8;
  const int k = idx & 255;
  const float v = (n < N) ? W[(size_t)k * N + n] : 0.0f;
  const _Float16 h = (_Float16)v;
  Wth[idx] = h;
  Wtl[idx] = (_Float16)(v - (float)h);
}

// concat [W_off | W_attn] -> transposed split, n-padded to NCATP; bias concat.
__global__ __launch_bounds__(256) void convert_cat_kernel(
    const float* __restrict__ Woff, const float* __restrict__ Wattn,
    const float* __restrict__ boff, const float* __restrict__ battn,
    _Float16* __restrict__ Wth, _Float16* __restrict__ Wtl,
    float* __restrict__ bcat) {
  const int idx = blockIdx.x * 256 + threadIdx.x;
  if (idx >= NCATP * 256) return;
  const int n = idx >> 8;
  const int k = idx & 255;
  float v = 0.0f;
  if (n < 96) v = Woff[(size_t)k * 96 + n];
  else if (n < NCAT) v = Wattn[(size_t)k * 48 + (n - 96)];
  const _Float16 h = (_Float16)v;
  Wth[idx] = h;
  Wtl[idx] = (_Float16)(v - (float)h);
  if (idx < NCAT) bcat[idx] = (idx < 96) ? boff[idx] : battn[idx - 96];
}

// ---------------------------------------------------------------------------
// C[M,N] = A[M,256] @ W[256,N] + bias via fp16x3 split MFMA.
// Barrier-free main loop:
//   - FULL A tile (64 x 256, fp16 hi/lo) staged to LDS once, XOR-swizzled
//     (byte ^= (row&7)<<4) so fragment b128 reads are ~2-way max; ONE barrier.
//   - 8 K-steps with NO barriers; B fragments register-prefetched from L2
//     one step ahead.
// 256 threads = 4 waves side-by-side in N; wave tile 64 x (FC*16).
// Fragment mapping verified end-to-end (rounds 3/4 passed):
//   A/B frag: lane&15 -> row/col, (lane>>4)*8+j -> k.
//   C/D:      col = lane&15, row = (lane>>4)*4 + reg.
// ---------------------------------------------------------------------------
template <int FC>
__global__ __launch_bounds__(256) void gemm3_kernel(
    const float* __restrict__ A, const _Float16* __restrict__ Bth,
    const _Float16* __restrict__ Btl, const float* __restrict__ bias,
    float* __restrict__ C, int M, int N) {
  constexpr int K = 256;
  __shared__ _Float16 Ah[64 * 256];   // swizzled layout, 32 KB
  __shared__ _Float16 Al[64 * 256];   // swizzled layout, 32 KB

  const int tid = threadIdx.x;
  const int wid = tid >> 6;
  const int lane = tid & 63;
  const int bm = blockIdx.x * 64;
  const int rsel = lane & 15;
  const int khi = (lane >> 4) * 8;    // k offset within a 32-k step (halfs)

  char* AhB = (char*)Ah;
  char* AlB = (char*)Al;

  // ---- stage the full 64x256 A tile (one barrier total) ----
#pragma unroll
  for (int it = 0; it < 16; ++it) {
    const int idx = it * 1024 + tid * 4;
    const int row = idx >> 8;
    const int col = idx & 255;
    float4 v = make_float4(0.f, 0.f, 0.f, 0.f);
    if (bm + row < M)
      v = *reinterpret_cast<const float4*>(&A[(size_t)(bm + row) * K + col]);
    f16x4 h, l;
    h[0] = (_Float16)v.x; l[0] = (_Float16)(v.x - (float)h[0]);
    h[1] = (_Float16)v.y; l[1] = (_Float16)(v.y - (float)h[1]);
    h[2] = (_Float16)v.z; l[2] = (_Float16)(v.z - (float)h[2]);
    h[3] = (_Float16)v.w; l[3] = (_Float16)(v.w - (float)h[3]);
    const int byt = row * 512 + ((col * 2) ^ ((row & 7) << 4));
    *reinterpret_cast<f16x4*>(AhB + byt) = h;
    *reinterpret_cast<f16x4*>(AlB + byt) = l;
  }

  // B fragment base pointers (this wave's FC col-groups)
  const _Float16* bhp = Bth + (size_t)(wid * FC * 16 + rsel) * K + khi;
  const _Float16* blp = Btl + (size_t)(wid * FC * 16 + rsel) * K + khi;

  f32x4 acc[4][FC];
#pragma unroll
  for (int fr = 0; fr < 4; ++fr)
#pragma unroll
    for (int fc = 0; fc < FC; ++fc) acc[fr][fc] = (f32x4)0.0f;

  // prologue: B for step 0
  f16x8 bh[FC], bl[FC];
#pragma unroll
  for (int fc = 0; fc < FC; ++fc) {
    bh[fc] = *reinterpret_cast<const f16x8*>(bhp + (size_t)fc * 16 * K);
    bl[fc] = *reinterpret_cast<const f16x8*>(blp + (size_t)fc * 16 * K);
  }

  __syncthreads();   // A tile ready; no further barriers

  const int swzx = (rsel & 7) << 4;   // per-lane row-XOR for fragment reads

#pragma unroll
  for (int s = 0; s < 8; ++s) {
    // ---- issue next-step B loads early (hide under MFMA) ----
    f16x8 nbh[FC], nbl[FC];
    if (s < 7) {
#pragma unroll
      for (int fc = 0; fc < FC; ++fc) {
        nbh[fc] = *reinterpret_cast<const f16x8*>(
            bhp + (size_t)fc * 16 * K + (s + 1) * 32);
        nbl[fc] = *reinterpret_cast<const f16x8*>(
            blp + (size_t)fc * 16 * K + (s + 1) * 32);
      }
    }
    // ---- A fragments from (swizzled) LDS ----
    f16x8 afh[4], afl[4];
#pragma unroll
    for (int fr = 0; fr < 4; ++fr) {
      const int row = fr * 16 + rsel;
      const int byt = row * 512 + (((s * 32 + khi) * 2) ^ swzx);
      afh[fr] = *reinterpret_cast<const f16x8*>(AhB + byt);
      afl[fr] = *reinterpret_cast<const f16x8*>(AlB + byt);
    }
    // ---- 3-term split MFMA:  Ah*Bh + Ah*Bl + Al*Bh ----
#pragma unroll
    for (int fr = 0; fr < 4; ++fr)
#pragma unroll
      for (int fc = 0; fc < FC; ++fc) {
        acc[fr][fc] = __builtin_amdgcn_mfma_f32_16x16x32_f16(
            afh[fr], bh[fc], acc[fr][fc], 0, 0, 0);
        acc[fr][fc] = __builtin_amdgcn_mfma_f32_16x16x32_f16(
            afh[fr], bl[fc], acc[fr][fc], 0, 0, 0);
        acc[fr][fc] = __builtin_amdgcn_mfma_f32_16x16x32_f16(
            afl[fr], bh[fc], acc[fr][fc], 0, 0, 0);
      }
    if (s < 7) {
#pragma unroll
      for (int fc = 0; fc < FC; ++fc) { bh[fc] = nbh[fc]; bl[fc] = nbl[fc]; }
    }
  }

  // ---- store with bias ----
  float bs_[FC];
#pragma unroll
  for (int fc = 0; fc < FC; ++fc) {
    const int col = wid * FC * 16 + fc * 16 + rsel;
    bs_[fc] = (col < N) ? bias[col] : 0.0f;
  }
#pragma unroll
  for (int fr = 0; fr < 4; ++fr)
#pragma unroll
    for (int i = 0; i < 4; ++i) {
      const int row = bm + fr * 16 + (lane >> 4) * 4 + i;
      if (row >= M) continue;
#pragma unroll
      for (int fc = 0; fc < FC; ++fc) {
        const int col = wid * FC * 16 + fc * 16 + rsel;
        if (col < N) C[(size_t)row * N + col] = acc[fr][fc][i] + bs_[fc];
      }
    }
}

// ---------------------------------------------------------------------------
// Sampling, prep/gather split. One block per (b,q); 3 fl-rows per block.
// Phase 1 (threads 0..143): for each (fl, h, l, p) compute softmax weight,
//   bilinear tap byte-offsets + weights ONCE -> LDS.
// Phase 2 (all 256 = 8 heads x 32 dims): pure gather: per point
//   2x ds_read_b128 (broadcast) + 4 global loads + 4 FMA.
// ---------------------------------------------------------------------------
__global__ __launch_bounds__(256) void sample2_kernel(
    const float* __restrict__ value, const float* __restrict__ refpts,
    const float* __restrict__ offs_attn, float* __restrict__ out_mid) {
  __shared__ int4   s_off[144];   // [fl*48 + h*6 + j] -> 4 tap byte offsets
  __shared__ float4 s_w[144];     // matching tap weights (attn*bilinear*valid)

  const int bq = blockIdx.x;       // b*900 + q
  const int b = bq / NQ;
  const int tid = threadIdx.x;

  if (tid < 144) {
    const int fl = tid / 48;
    const int rem = tid - fl * 48;  // h*6 + j
    const int h = rem / 6;
    const int j = rem - h * 6;
    const int l = j >> 1;

    const int LVL_W[3] = {100, 50, 25};
    const int LVL_BASE[3] = {0, 10000, 12500};
    const int W = LVL_W[l];
    const int base = LVL_BASE[l];
    const float fW = (float)W, fH = (float)W;  // square levels

    const int row = bq * 3 + fl;
    const float* oa = offs_attn + (size_t)row * NCAT;

    // softmax over this head's 6 logits
    float aw[6];
    float mx = -INFINITY;
#pragma unroll
    for (int jj = 0; jj < 6; ++jj) {
      aw[jj] = oa[96 + h * 6 + jj];
      mx = fmaxf(mx, aw[jj]);
    }
    float ssum = 0.f;
#pragma unroll
    for (int jj = 0; jj < 6; ++jj) ssum += expf(aw[jj] - mx);
    const float wa = expf(aw[j] - mx) / ssum;

    const float rx = refpts[(size_t)row * 2 + 0];
    const float ry = refpts[(size_t)row * 2 + 1];
    const float ox = oa[h * 12 + j * 2 + 0];
    const float oy = oa[h * 12 + j * 2 + 1];
    const float x = (rx + ox / fW) * fW - 0.5f;
    const float y = (ry + oy / fH) * fH - 0.5f;
    const float x0 = floorf(x);
    const float y0 = floorf(y);

    int offv[4];
    float wv[4];
#pragma unroll
    for (int dy = 0; dy < 2; ++dy)
#pragma unroll
      for (int dx = 0; dx < 2; ++dx) {
        const float xi = x0 + (float)dx;
        const float yi = y0 + (float)dy;
        const float wgt = (1.0f - fabsf(x - xi)) * (1.0f - fabsf(y - yi));
        const bool valid = (xi >= 0.f) && (xi <= fW - 1.f) &&
                           (yi >= 0.f) && (yi <= fH - 1.f);
        const int xic = (int)fminf(fmaxf(xi, 0.f), fW - 1.f);
        const int yic = (int)fminf(fmaxf(yi, 0.f), fH - 1.f);
        const int pos = base + yic * W + xic;
        offv[dy * 2 + dx] = pos * 1024;          // byte offset of row, ch 0
        wv[dy * 2 + dx] = valid ? wgt * wa : 0.0f;
      }
    s_off[tid] = make_int4(offv[0], offv[1], offv[2], offv[3]);
    s_w[tid] = make_float4(wv[0], wv[1], wv[2], wv[3]);
  }
  __syncthreads();

  const int h = tid >> 5;
  const int d = tid & 31;
  const char* vb = (const char*)value +
                   ((size_t)b * LEN_IN * 256 + h * 32 + d) * 4;

#pragma unroll
  for (int fl = 0; fl < 3; ++fl) {
    float acc = 0.f;
#pragma unroll
    for (int j = 0; j < 6; ++j) {
      const int rec = fl * 48 + h * 6 + j;
      const int4 o = s_off[rec];
      const float4 w = s_w[rec];
      acc = fmaf(w.x, *(const float*)(vb + o.x), acc);
      acc = fmaf(w.y, *(const float*)(vb + o.y), acc);
      acc = fmaf(w.z, *(const float*)(vb + o.z), acc);
      acc = fmaf(w.w, *(const float*)(vb + o.w), acc);
    }
    out_mid[((size_t)bq * 3 + fl) * 256 + tid] = acc;
  }
}

// ---------------------------------------------------------------------------
extern "C" void kernel_launch(void* const* d_in, const int* in_sizes, int n_in,
                              void* d_out, int out_size, void* d_ws,
                              size_t ws_size, hipStream_t stream) {
  const float* query   = (const float*)d_in[0];   // [16,900,3,256]
  const float* refpts  = (const float*)d_in[1];   // [16,900,3,2]
  const float* in_flat = (const float*)d_in[2];   // [16,13125,256]
  // d_in[3]: spatial shapes (static, hardcoded)
  const float* W_value = (const float*)d_in[4];
  const float* b_value = (const float*)d_in[5];
  const float* W_off   = (const float*)d_in[6];
  const float* b_off   = (const float*)d_in[7];
  const float* W_attn  = (const float*)d_in[8];
  const float* b_attn  = (const float*)d_in[9];
  const float* W_out   = (const float*)d_in[10];
  const float* b_out   = (const float*)d_in[11];
  float* out = (float*)d_out;

  char* ws = (char*)d_ws;
  float* value     = (float*)ws; ws += (size_t)M_V * 256 * sizeof(float);
  float* out_mid   = (float*)ws; ws += (size_t)M_Q * 256 * sizeof(float);
  float* offs_attn = (float*)ws; ws += (size_t)M_Q * NCAT * sizeof(float);
  _Float16* Wvh = (_Float16*)ws; ws += 256 * 256 * sizeof(_Float16);
  _Float16* Wvl = (_Float16*)ws; ws += 256 * 256 * sizeof(_Float16);
  _Float16* Woh = (_Float16*)ws; ws += 256 * 256 * sizeof(_Float16);
  _Float16* Wol = (_Float16*)ws; ws += 256 * 256 * sizeof(_Float16);
  _Float16* Wch = (_Float16*)ws; ws += NCATP * 256 * sizeof(_Float16);
  _Float16* Wcl = (_Float16*)ws; ws += NCATP * 256 * sizeof(_Float16);
  float* bcat   = (float*)ws;    ws += 256 * sizeof(float);

  const dim3 blk(256);

  // ---- weight prep (tiny) ----
  convert_weight_kernel<<<dim3(256), blk, 0, stream>>>(W_value, Wvh, Wvl, 256, 256);
  convert_weight_kernel<<<dim3(256), blk, 0, stream>>>(W_out,   Woh, Wol, 256, 256);
  convert_cat_kernel<<<dim3(NCATP), blk, 0, stream>>>(W_off, W_attn, b_off, b_attn,
                                                      Wch, Wcl, bcat);

  // 1) value = input_flatten @ W_value + b_value   (210000 x 256 x 256)
  gemm3_kernel<4><<<dim3((M_V + 63) / 64), blk, 0, stream>>>(
      in_flat, Wvh, Wvl, b_value, value, M_V, 256);

  // 2) [offsets | attn logits] = query @ Wcat + bcat   (43200 x 144 x 256)
  gemm3_kernel<3><<<dim3((M_Q + 63) / 64), blk, 0, stream>>>(
      query, Wch, Wcl, bcat, offs_attn, M_Q, NCAT);

  // 3) softmax + bilinear sampling + weighted sum -> out_mid
  sample2_kernel<<<dim3(BS * NQ), blk, 0, stream>>>(value, refpts, offs_attn,
                                                    out_mid);

  // 4) out = out_mid @ W_out + b_out   (43200 x 256 x 256)
  gemm3_kernel<4><<<dim3((M_Q + 63) / 64), blk, 0, stream>>>(
      out_mid, Woh, Wol, b_out, out, M_Q, 256);
}

// Round 8
// 777.839 us; speedup vs baseline: 1.0978x; 1.0978x over previous
//
#include <hip/hip_runtime.h>
#include <math.h>

// ---- problem constants (static per reference) ----
#define D_MODEL   256
#define N_HEADS   8
#define HEAD_DIM  32
#define N_LEVELS  3
#define N_POINTS  2
#define BS        16
#define NQ        900
#define LEN_IN    13125
#define M_Q       (BS * NQ * N_LEVELS)   // 43200
#define M_V       (BS * LEN_IN)          // 210000
#define NCAT      144                    // 96 offset cols + 48 attn cols
#define NCATP     256                    // padded so 2 col-blocks of 128 fit

typedef _Float16 f16x8 __attribute__((ext_vector_type(8)));
typedef _Float16 f16x4 __attribute__((ext_vector_type(4)));
typedef float f32x4 __attribute__((ext_vector_type(4)));

// ---------------------------------------------------------------------------
// Weight prep -> FRAGMENT-MAJOR layout.
// Source W[K=256][N] fp32. Split v = hi(fp16) + lo(fp16).
// Dst index for (n,k):  ((n>>4)*32 + (k>>3))*128 + (n&15)*8 + (k&7)
// so a wave's B-fragment (16 cols x 8 ks) is one contiguous 1 KB block:
// addr = g*4096 + s*512 + lane*8 halfs  (g = n-group, s = 32-k step).
// ---------------------------------------------------------------------------
__global__ __launch_bounds__(256) void convert_weight_kernel(
    const float* __restrict__ W, _Float16* __restrict__ Wph,
    _Float16* __restrict__ Wpl, int N, int Npad) {
  const int idx = blockIdx.x * 256 + threadIdx.x;
  if (idx >= Npad * 256) return;
  const int n = idx >> 8;
  const int k = idx & 255;
  const float v = (n < N) ? W[(size_t)k * N + n] : 0.0f;
  const _Float16 h = (_Float16)v;
  const int dst = (((n >> 4) * 32) + (k >> 3)) * 128 + (n & 15) * 8 + (k & 7);
  Wph[dst] = h;
  Wpl[dst] = (_Float16)(v - (float)h);
}

// concat [W_off | W_attn] -> fragment-major split, n-padded to NCATP; bias cat.
__global__ __launch_bounds__(256) void convert_cat_kernel(
    const float* __restrict__ Woff, const float* __restrict__ Wattn,
    const float* __restrict__ boff, const float* __restrict__ battn,
    _Float16* __restrict__ Wph, _Float16* __restrict__ Wpl,
    float* __restrict__ bcat) {
  const int idx = blockIdx.x * 256 + threadIdx.x;
  if (idx >= NCATP * 256) return;
  const int n = idx >> 8;
  const int k = idx & 255;
  float v = 0.0f;
  if (n < 96) v = Woff[(size_t)k * 96 + n];
  else if (n < NCAT) v = Wattn[(size_t)k * 48 + (n - 96)];
  const _Float16 h = (_Float16)v;
  const int dst = (((n >> 4) * 32) + (k >> 3)) * 128 + (n & 15) * 8 + (k & 7);
  Wph[dst] = h;
  Wpl[dst] = (_Float16)(v - (float)h);
  if (idx < NCAT) bcat[idx] = (idx < 96) ? boff[idx] : battn[idx - 96];
}

// ---------------------------------------------------------------------------
// C[M,N] = A[M,256] @ W[256,N] + bias via fp16x3 split MFMA.
// Occupancy-first design: FC=2 -> acc 32 regs; target <=128 unified VGPR
// (launch_bounds (256,4) => 16 waves/CU); 32 KB LDS => 4 blocks/CU.
// Block tile 64 x 128 (4 waves side by side, wave tile 64x32).
// A staged in two 64x128-k chunks (fp16 hi/lo, XOR-swizzled byte^=(row&7)<<4).
// B read direct from L2 in fragment-major layout: 1 contiguous KB per load.
// MFMA trios reordered term-major (dep distance 8 instructions).
// Fragment mapping verified end-to-end (rounds 3-5 passed):
//   A/B frag: lane&15 -> row/col, (lane>>4)*8+j -> k.
//   C/D:      col = lane&15, row = (lane>>4)*4 + reg.
// ---------------------------------------------------------------------------
template <int FC, int TAG>
__global__ __launch_bounds__(256, 4) void gemm4_kernel(
    const float* __restrict__ A, const _Float16* __restrict__ Bph,
    const _Float16* __restrict__ Bpl, const float* __restrict__ bias,
    float* __restrict__ C, int M, int N) {
  constexpr int K = 256;
  __shared__ _Float16 AhL[64 * 128];   // 16 KB, swizzled
  __shared__ _Float16 AlL[64 * 128];   // 16 KB, swizzled

  const int tid = threadIdx.x;
  const int wid = tid >> 6;
  const int lane = tid & 63;
  const int bx = blockIdx.x;           // col block (128 cols)
  const int bm = blockIdx.y * 64;
  const int rsel = lane & 15;
  const int q = (lane >> 4) & 3;
  const int swzx = (rsel & 7) << 4;

  char* AhB = (char*)AhL;
  char* AlB = (char*)AlL;

  // B fragment-major base pointers: g = n-group = bx*8 + wid*2 + fc
  const _Float16* bph[FC];
  const _Float16* bpl[FC];
#pragma unroll
  for (int fc = 0; fc < FC; ++fc) {
    const int g = bx * 8 + wid * 2 + fc;
    bph[fc] = Bph + (size_t)g * 4096 + lane * 8;
    bpl[fc] = Bpl + (size_t)g * 4096 + lane * 8;
  }

  f32x4 acc[4][FC];
#pragma unroll
  for (int fr = 0; fr < 4; ++fr)
#pragma unroll
    for (int fc = 0; fc < FC; ++fc) acc[fr][fc] = (f32x4)0.0f;

#pragma unroll
  for (int c = 0; c < 2; ++c) {
    // ---- stage A chunk c: 64 rows x 128 k, fp32->fp16 hi/lo, swizzled ----
    if (c == 1) __syncthreads();   // all waves done reading chunk 0
#pragma unroll
    for (int it = 0; it < 8; ++it) {
      const int i = it * 1024 + tid * 4;
      const int row = i >> 7;
      const int col = i & 127;
      float4 v = make_float4(0.f, 0.f, 0.f, 0.f);
      if (bm + row < M)
        v = *reinterpret_cast<const float4*>(
            &A[(size_t)(bm + row) * K + c * 128 + col]);
      f16x4 h, l;
      h[0] = (_Float16)v.x; l[0] = (_Float16)(v.x - (float)h[0]);
      h[1] = (_Float16)v.y; l[1] = (_Float16)(v.y - (float)h[1]);
      h[2] = (_Float16)v.z; l[2] = (_Float16)(v.z - (float)h[2]);
      h[3] = (_Float16)v.w; l[3] = (_Float16)(v.w - (float)h[3]);
      const int byt = row * 256 + ((col * 2) ^ ((row & 7) << 4));
      *reinterpret_cast<f16x4*>(AhB + byt) = h;
      *reinterpret_cast<f16x4*>(AlB + byt) = l;
    }
    __syncthreads();

    // ---- 4 K-steps of 32 on this chunk ----
#pragma unroll
    for (int sl = 0; sl < 4; ++sl) {
      const int s = c * 4 + sl;
      f16x8 bh[FC], bl[FC], afh[4], afl[4];
#pragma unroll
      for (int fc = 0; fc < FC; ++fc) {
        bh[fc] = *reinterpret_cast<const f16x8*>(bph[fc] + s * 512);
        bl[fc] = *reinterpret_cast<const f16x8*>(bpl[fc] + s * 512);
      }
#pragma unroll
      for (int fr = 0; fr < 4; ++fr) {
        const int row = fr * 16 + rsel;
        const int byt = row * 256 + ((sl * 64 + q * 16) ^ swzx);
        afh[fr] = *reinterpret_cast<const f16x8*>(AhB + byt);
        afl[fr] = *reinterpret_cast<const f16x8*>(AlB + byt);
      }
      __builtin_amdgcn_s_setprio(1);
      // term-major: consecutive MFMAs independent (dep distance = 4*FC)
#pragma unroll
      for (int fr = 0; fr < 4; ++fr)
#pragma unroll
        for (int fc = 0; fc < FC; ++fc)
          acc[fr][fc] = __builtin_amdgcn_mfma_f32_16x16x32_f16(
              afh[fr], bh[fc], acc[fr][fc], 0, 0, 0);
#pragma unroll
      for (int fr = 0; fr < 4; ++fr)
#pragma unroll
        for (int fc = 0; fc < FC; ++fc)
          acc[fr][fc] = __builtin_amdgcn_mfma_f32_16x16x32_f16(
              afh[fr], bl[fc], acc[fr][fc], 0, 0, 0);
#pragma unroll
      for (int fr = 0; fr < 4; ++fr)
#pragma unroll
        for (int fc = 0; fc < FC; ++fc)
          acc[fr][fc] = __builtin_amdgcn_mfma_f32_16x16x32_f16(
              afl[fr], bh[fc], acc[fr][fc], 0, 0, 0);
      __builtin_amdgcn_s_setprio(0);
    }
  }

  // ---- store with bias ----
  const int colbase = bx * 128 + wid * 32;
  float bs_[FC];
#pragma unroll
  for (int fc = 0; fc < FC; ++fc) {
    const int col = colbase + fc * 16 + rsel;
    bs_[fc] = (col < N) ? bias[col] : 0.0f;
  }
#pragma unroll
  for (int fr = 0; fr < 4; ++fr)
#pragma unroll
    for (int i = 0; i < 4; ++i) {
      const int row = bm + fr * 16 + (lane >> 4) * 4 + i;
      if (row >= M) continue;
#pragma unroll
      for (int fc = 0; fc < FC; ++fc) {
        const int col = colbase + fc * 16 + rsel;
        if (col < N) C[(size_t)row * N + col] = acc[fr][fc][i] + bs_[fc];
      }
    }
}

// ---------------------------------------------------------------------------
// Sampling, prep/gather split. One block per (b,q); 3 fl-rows per block.
// Phase 1 (threads 0..143): per (fl,h,l,p) softmax weight + 4 tap
//   byte-offsets/weights -> LDS.  Phase 2 (8 heads x 32 dims): pure gather.
// ---------------------------------------------------------------------------
__global__ __launch_bounds__(256) void sample2_kernel(
    const float* __restrict__ value, const float* __restrict__ refpts,
    const float* __restrict__ offs_attn, float* __restrict__ out_mid) {
  __shared__ int4   s_off[144];
  __shared__ float4 s_w[144];

  const int bq = blockIdx.x;       // b*900 + q
  const int b = bq / NQ;
  const int tid = threadIdx.x;

  if (tid < 144) {
    const int fl = tid / 48;
    const int rem = tid - fl * 48;  // h*6 + j
    const int h = rem / 6;
    const int j = rem - h * 6;
    const int l = j >> 1;

    const int LVL_W[3] = {100, 50, 25};
    const int LVL_BASE[3] = {0, 10000, 12500};
    const int W = LVL_W[l];
    const int base = LVL_BASE[l];
    const float fW = (float)W, fH = (float)W;  // square levels

    const int row = bq * 3 + fl;
    const float* oa = offs_attn + (size_t)row * NCAT;

    float aw[6];
    float mx = -INFINITY;
#pragma unroll
    for (int jj = 0; jj < 6; ++jj) {
      aw[jj] = oa[96 + h * 6 + jj];
      mx = fmaxf(mx, aw[jj]);
    }
    float ssum = 0.f;
#pragma unroll
    for (int jj = 0; jj < 6; ++jj) ssum += expf(aw[jj] - mx);
    const float wa = expf(aw[j] - mx) / ssum;

    const float rx = refpts[(size_t)row * 2 + 0];
    const float ry = refpts[(size_t)row * 2 + 1];
    const float ox = oa[h * 12 + j * 2 + 0];
    const float oy = oa[h * 12 + j * 2 + 1];
    const float x = (rx + ox / fW) * fW - 0.5f;
    const float y = (ry + oy / fH) * fH - 0.5f;
    const float x0 = floorf(x);
    const float y0 = floorf(y);

    int offv[4];
    float wv[4];
#pragma unroll
    for (int dy = 0; dy < 2; ++dy)
#pragma unroll
      for (int dx = 0; dx < 2; ++dx) {
        const float xi = x0 + (float)dx;
        const float yi = y0 + (float)dy;
        const float wgt = (1.0f - fabsf(x - xi)) * (1.0f - fabsf(y - yi));
        const bool valid = (xi >= 0.f) && (xi <= fW - 1.f) &&
                           (yi >= 0.f) && (yi <= fH - 1.f);
        const int xic = (int)fminf(fmaxf(xi, 0.f), fW - 1.f);
        const int yic = (int)fminf(fmaxf(yi, 0.f), fH - 1.f);
        const int pos = base + yic * W + xic;
        offv[dy * 2 + dx] = pos * 1024;
        wv[dy * 2 + dx] = valid ? wgt * wa : 0.0f;
      }
    s_off[tid] = make_int4(offv[0], offv[1], offv[2], offv[3]);
    s_w[tid] = make_float4(wv[0], wv[1], wv[2], wv[3]);
  }
  __syncthreads();

  const int h = tid >> 5;
  const int d = tid & 31;
  const char* vb = (const char*)value +
                   ((size_t)b * LEN_IN * 256 + h * 32 + d) * 4;

#pragma unroll
  for (int fl = 0; fl < 3; ++fl) {
    float acc = 0.f;
#pragma unroll
    for (int j = 0; j < 6; ++j) {
      const int rec = fl * 48 + h * 6 + j;
      const int4 o = s_off[rec];
      const float4 w = s_w[rec];
      acc = fmaf(w.x, *(const float*)(vb + o.x), acc);
      acc = fmaf(w.y, *(const float*)(vb + o.y), acc);
      acc = fmaf(w.z, *(const float*)(vb + o.z), acc);
      acc = fmaf(w.w, *(const float*)(vb + o.w), acc);
    }
    out_mid[((size_t)bq * 3 + fl) * 256 + tid] = acc;
  }
}

// ---------------------------------------------------------------------------
extern "C" void kernel_launch(void* const* d_in, const int* in_sizes, int n_in,
                              void* d_out, int out_size, void* d_ws,
                              size_t ws_size, hipStream_t stream) {
  const float* query   = (const float*)d_in[0];   // [16,900,3,256]
  const float* refpts  = (const float*)d_in[1];   // [16,900,3,2]
  const float* in_flat = (const float*)d_in[2];   // [16,13125,256]
  // d_in[3]: spatial shapes (static, hardcoded)
  const float* W_value = (const float*)d_in[4];
  const float* b_value = (const float*)d_in[5];
  const float* W_off   = (const float*)d_in[6];
  const float* b_off   = (const float*)d_in[7];
  const float* W_attn  = (const float*)d_in[8];
  const float* b_attn  = (const float*)d_in[9];
  const float* W_out   = (const float*)d_in[10];
  const float* b_out   = (const float*)d_in[11];
  float* out = (float*)d_out;

  char* ws = (char*)d_ws;
  float* value     = (float*)ws; ws += (size_t)M_V * 256 * sizeof(float);
  float* out_mid   = (float*)ws; ws += (size_t)M_Q * 256 * sizeof(float);
  float* offs_attn = (float*)ws; ws += (size_t)M_Q * NCAT * sizeof(float);
  _Float16* Wvh = (_Float16*)ws; ws += 256 * 256 * sizeof(_Float16);
  _Float16* Wvl = (_Float16*)ws; ws += 256 * 256 * sizeof(_Float16);
  _Float16* Woh = (_Float16*)ws; ws += 256 * 256 * sizeof(_Float16);
  _Float16* Wol = (_Float16*)ws; ws += 256 * 256 * sizeof(_Float16);
  _Float16* Wch = (_Float16*)ws; ws += NCATP * 256 * sizeof(_Float16);
  _Float16* Wcl = (_Float16*)ws; ws += NCATP * 256 * sizeof(_Float16);
  float* bcat   = (float*)ws;    ws += 256 * sizeof(float);

  const dim3 blk(256);

  // ---- weight prep (tiny) ----
  convert_weight_kernel<<<dim3(256), blk, 0, stream>>>(W_value, Wvh, Wvl, 256, 256);
  convert_weight_kernel<<<dim3(256), blk, 0, stream>>>(W_out,   Woh, Wol, 256, 256);
  convert_cat_kernel<<<dim3(NCATP), blk, 0, stream>>>(W_off, W_attn, b_off, b_attn,
                                                      Wch, Wcl, bcat);

  // 1) value = input_flatten @ W_value + b_value   (210000 x 256 x 256)
  gemm4_kernel<2, 1><<<dim3(2, (M_V + 63) / 64), blk, 0, stream>>>(
      in_flat, Wvh, Wvl, b_value, value, M_V, 256);

  // 2) [offsets | attn logits] = query @ Wcat + bcat   (43200 x 144 x 256)
  gemm4_kernel<2, 2><<<dim3(2, (M_Q + 63) / 64), blk, 0, stream>>>(
      query, Wch, Wcl, bcat, offs_attn, M_Q, NCAT);

  // 3) softmax + bilinear sampling + weighted sum -> out_mid
  sample2_kernel<<<dim3(BS * NQ), blk, 0, stream>>>(value, refpts, offs_attn,
                                                    out_mid);

  // 4) out = out_mid @ W_out + b_out   (43200 x 256 x 256)
  gemm4_kernel<2, 3><<<dim3(2, (M_Q + 63) / 64), blk, 0, stream>>>(
      out_mid, Woh, Wol, b_out, out, M_Q, 256);
}

// Round 10
// 717.827 us; speedup vs baseline: 1.1896x; 1.0836x over previous
//
#include <hip/hip_runtime.h>
#include <math.h>

// ---- problem constants (static per reference) ----
#define D_MODEL   256
#define N_HEADS   8
#define HEAD_DIM  32
#define N_LEVELS  3
#define N_POINTS  2
#define BS        16
#define NQ        900
#define LEN_IN    13125
#define M_Q       (BS * NQ * N_LEVELS)   // 43200
#define M_V       (BS * LEN_IN)          // 210000
#define NCAT      144                    // 96 offset cols + 48 attn cols
#define NCATP     256                    // padded so 2 col-blocks of 128 fit

typedef _Float16 f16x8 __attribute__((ext_vector_type(8)));
typedef _Float16 f16x4 __attribute__((ext_vector_type(4)));
typedef float f32x4 __attribute__((ext_vector_type(4)));

// ---------------------------------------------------------------------------
// Weight prep -> FRAGMENT-MAJOR layout.
// Source W[K=256][N] fp32. Split v = hi(fp16) + lo(fp16).
// Dst index for (n,k):  ((n>>4)*32 + (k>>3))*128 + (n&15)*8 + (k&7)
// so a wave's B-fragment (16 cols x 8 ks) is one contiguous 1 KB block:
// addr = g*4096 + s*512 + lane*8 halfs  (g = n-group, s = 32-k step).
// ---------------------------------------------------------------------------
__global__ __launch_bounds__(256) void convert_weight_kernel(
    const float* __restrict__ W, _Float16* __restrict__ Wph,
    _Float16* __restrict__ Wpl, int N, int Npad) {
  const int idx = blockIdx.x * 256 + threadIdx.x;
  if (idx >= Npad * 256) return;
  const int n = idx >> 8;
  const int k = idx & 255;
  const float v = (n < N) ? W[(size_t)k * N + n] : 0.0f;
  const _Float16 h = (_Float16)v;
  const int dst = (((n >> 4) * 32) + (k >> 3)) * 128 + (n & 15) * 8 + (k & 7);
  Wph[dst] = h;
  Wpl[dst] = (_Float16)(v - (float)h);
}

// concat [W_off | W_attn] -> fragment-major split, n-padded to NCATP; bias cat.
__global__ __launch_bounds__(256) void convert_cat_kernel(
    const float* __restrict__ Woff, const float* __restrict__ Wattn,
    const float* __restrict__ boff, const float* __restrict__ battn,
    _Float16* __restrict__ Wph, _Float16* __restrict__ Wpl,
    float* __restrict__ bcat) {
  const int idx = blockIdx.x * 256 + threadIdx.x;
  if (idx >= NCATP * 256) return;
  const int n = idx >> 8;
  const int k = idx & 255;
  float v = 0.0f;
  if (n < 96) v = Woff[(size_t)k * 96 + n];
  else if (n < NCAT) v = Wattn[(size_t)k * 48 + (n - 96)];
  const _Float16 h = (_Float16)v;
  const int dst = (((n >> 4) * 32) + (k >> 3)) * 128 + (n & 15) * 8 + (k & 7);
  Wph[dst] = h;
  Wpl[dst] = (_Float16)(v - (float)h);
  if (idx < NCAT) bcat[idx] = (idx < 96) ? boff[idx] : battn[idx - 96];
}

// ---------------------------------------------------------------------------
// C[M,N] = A[M,256] @ W[256,N] + bias via fp16x3 split MFMA (A fp32 input).
// Occupancy-first: FC=2, 32 KB LDS, launch_bounds(256,4).
// OutT selects the C store type (float or _Float16).
// Fragment mapping verified end-to-end (rounds 3-8 passed).
// ---------------------------------------------------------------------------
template <int FC, int TAG, typename OutT>
__global__ __launch_bounds__(256, 4) void gemm4_kernel(
    const float* __restrict__ A, const _Float16* __restrict__ Bph,
    const _Float16* __restrict__ Bpl, const float* __restrict__ bias,
    OutT* __restrict__ C, int M, int N) {
  constexpr int K = 256;
  __shared__ _Float16 AhL[64 * 128];   // 16 KB, swizzled
  __shared__ _Float16 AlL[64 * 128];   // 16 KB, swizzled

  const int tid = threadIdx.x;
  const int wid = tid >> 6;
  const int lane = tid & 63;
  const int bx = blockIdx.x;           // col block (128 cols)
  const int bm = blockIdx.y * 64;
  const int rsel = lane & 15;
  const int q = (lane >> 4) & 3;
  const int swzx = (rsel & 7) << 4;

  char* AhB = (char*)AhL;
  char* AlB = (char*)AlL;

  const _Float16* bph[FC];
  const _Float16* bpl[FC];
#pragma unroll
  for (int fc = 0; fc < FC; ++fc) {
    const int g = bx * 8 + wid * 2 + fc;
    bph[fc] = Bph + (size_t)g * 4096 + lane * 8;
    bpl[fc] = Bpl + (size_t)g * 4096 + lane * 8;
  }

  f32x4 acc[4][FC];
#pragma unroll
  for (int fr = 0; fr < 4; ++fr)
#pragma unroll
    for (int fc = 0; fc < FC; ++fc) acc[fr][fc] = (f32x4)0.0f;

#pragma unroll
  for (int c = 0; c < 2; ++c) {
    if (c == 1) __syncthreads();
#pragma unroll
    for (int it = 0; it < 8; ++it) {
      const int i = it * 1024 + tid * 4;
      const int row = i >> 7;
      const int col = i & 127;
      float4 v = make_float4(0.f, 0.f, 0.f, 0.f);
      if (bm + row < M)
        v = *reinterpret_cast<const float4*>(
            &A[(size_t)(bm + row) * K + c * 128 + col]);
      f16x4 h, l;
      h[0] = (_Float16)v.x; l[0] = (_Float16)(v.x - (float)h[0]);
      h[1] = (_Float16)v.y; l[1] = (_Float16)(v.y - (float)h[1]);
      h[2] = (_Float16)v.z; l[2] = (_Float16)(v.z - (float)h[2]);
      h[3] = (_Float16)v.w; l[3] = (_Float16)(v.w - (float)h[3]);
      const int byt = row * 256 + ((col * 2) ^ ((row & 7) << 4));
      *reinterpret_cast<f16x4*>(AhB + byt) = h;
      *reinterpret_cast<f16x4*>(AlB + byt) = l;
    }
    __syncthreads();

#pragma unroll
    for (int sl = 0; sl < 4; ++sl) {
      const int s = c * 4 + sl;
      f16x8 bh[FC], bl[FC], afh[4], afl[4];
#pragma unroll
      for (int fc = 0; fc < FC; ++fc) {
        bh[fc] = *reinterpret_cast<const f16x8*>(bph[fc] + s * 512);
        bl[fc] = *reinterpret_cast<const f16x8*>(bpl[fc] + s * 512);
      }
#pragma unroll
      for (int fr = 0; fr < 4; ++fr) {
        const int row = fr * 16 + rsel;
        const int byt = row * 256 + ((sl * 64 + q * 16) ^ swzx);
        afh[fr] = *reinterpret_cast<const f16x8*>(AhB + byt);
        afl[fr] = *reinterpret_cast<const f16x8*>(AlB + byt);
      }
      __builtin_amdgcn_s_setprio(1);
#pragma unroll
      for (int fr = 0; fr < 4; ++fr)
#pragma unroll
        for (int fc = 0; fc < FC; ++fc)
          acc[fr][fc] = __builtin_amdgcn_mfma_f32_16x16x32_f16(
              afh[fr], bh[fc], acc[fr][fc], 0, 0, 0);
#pragma unroll
      for (int fr = 0; fr < 4; ++fr)
#pragma unroll
        for (int fc = 0; fc < FC; ++fc)
          acc[fr][fc] = __builtin_amdgcn_mfma_f32_16x16x32_f16(
              afh[fr], bl[fc], acc[fr][fc], 0, 0, 0);
#pragma unroll
      for (int fr = 0; fr < 4; ++fr)
#pragma unroll
        for (int fc = 0; fc < FC; ++fc)
          acc[fr][fc] = __builtin_amdgcn_mfma_f32_16x16x32_f16(
              afl[fr], bh[fc], acc[fr][fc], 0, 0, 0);
      __builtin_amdgcn_s_setprio(0);
    }
  }

  const int colbase = bx * 128 + wid * 32;
  float bs_[FC];
#pragma unroll
  for (int fc = 0; fc < FC; ++fc) {
    const int col = colbase + fc * 16 + rsel;
    bs_[fc] = (col < N) ? bias[col] : 0.0f;
  }
#pragma unroll
  for (int fr = 0; fr < 4; ++fr)
#pragma unroll
    for (int i = 0; i < 4; ++i) {
      const int row = bm + fr * 16 + (lane >> 4) * 4 + i;
      if (row >= M) continue;
#pragma unroll
      for (int fc = 0; fc < FC; ++fc) {
        const int col = colbase + fc * 16 + rsel;
        if (col < N) C[(size_t)row * N + col] = (OutT)(acc[fr][fc][i] + bs_[fc]);
      }
    }
}

// ---------------------------------------------------------------------------
// out = out_mid(fp16) @ W_out + b_out.  A is EXACT fp16 -> 2-term MFMA
// (A*Bh + A*Bl), no A-split, 16 KB LDS.
// ---------------------------------------------------------------------------
template <int FC>
__global__ __launch_bounds__(256, 4) void gemm5_kernel(
    const _Float16* __restrict__ A, const _Float16* __restrict__ Bph,
    const _Float16* __restrict__ Bpl, const float* __restrict__ bias,
    float* __restrict__ C, int M, int N) {
  constexpr int K = 256;
  __shared__ _Float16 AhL[64 * 128];   // 16 KB, swizzled

  const int tid = threadIdx.x;
  const int wid = tid >> 6;
  const int lane = tid & 63;
  const int bx = blockIdx.x;
  const int bm = blockIdx.y * 64;
  const int rsel = lane & 15;
  const int q = (lane >> 4) & 3;
  const int swzx = (rsel & 7) << 4;

  char* AhB = (char*)AhL;

  const _Float16* bph[FC];
  const _Float16* bpl[FC];
#pragma unroll
  for (int fc = 0; fc < FC; ++fc) {
    const int g = bx * 8 + wid * 2 + fc;
    bph[fc] = Bph + (size_t)g * 4096 + lane * 8;
    bpl[fc] = Bpl + (size_t)g * 4096 + lane * 8;
  }

  f32x4 acc[4][FC];
#pragma unroll
  for (int fr = 0; fr < 4; ++fr)
#pragma unroll
    for (int fc = 0; fc < FC; ++fc) acc[fr][fc] = (f32x4)0.0f;

#pragma unroll
  for (int c = 0; c < 2; ++c) {
    if (c == 1) __syncthreads();
    // stage 64 rows x 128 halfs (fp16 direct copy, swizzled)
#pragma unroll
    for (int it = 0; it < 4; ++it) {
      const int i = it * 2048 + tid * 8;
      const int row = i >> 7;
      const int col = i & 127;
      f16x8 v = (f16x8)(_Float16)0;
      if (bm + row < M)
        v = *reinterpret_cast<const f16x8*>(
            &A[(size_t)(bm + row) * K + c * 128 + col]);
      const int byt = row * 256 + ((col * 2) ^ ((row & 7) << 4));
      *reinterpret_cast<f16x8*>(AhB + byt) = v;
    }
    __syncthreads();

#pragma unroll
    for (int sl = 0; sl < 4; ++sl) {
      const int s = c * 4 + sl;
      f16x8 bh[FC], bl[FC], afh[4];
#pragma unroll
      for (int fc = 0; fc < FC; ++fc) {
        bh[fc] = *reinterpret_cast<const f16x8*>(bph[fc] + s * 512);
        bl[fc] = *reinterpret_cast<const f16x8*>(bpl[fc] + s * 512);
      }
#pragma unroll
      for (int fr = 0; fr < 4; ++fr) {
        const int row = fr * 16 + rsel;
        const int byt = row * 256 + ((sl * 64 + q * 16) ^ swzx);
        afh[fr] = *reinterpret_cast<const f16x8*>(AhB + byt);
      }
      __builtin_amdgcn_s_setprio(1);
#pragma unroll
      for (int fr = 0; fr < 4; ++fr)
#pragma unroll
        for (int fc = 0; fc < FC; ++fc)
          acc[fr][fc] = __builtin_amdgcn_mfma_f32_16x16x32_f16(
              afh[fr], bh[fc], acc[fr][fc], 0, 0, 0);
#pragma unroll
      for (int fr = 0; fr < 4; ++fr)
#pragma unroll
        for (int fc = 0; fc < FC; ++fc)
          acc[fr][fc] = __builtin_amdgcn_mfma_f32_16x16x32_f16(
              afh[fr], bl[fc], acc[fr][fc], 0, 0, 0);
      __builtin_amdgcn_s_setprio(0);
    }
  }

  const int colbase = bx * 128 + wid * 32;
  float bs_[FC];
#pragma unroll
  for (int fc = 0; fc < FC; ++fc) {
    const int col = colbase + fc * 16 + rsel;
    bs_[fc] = (col < N) ? bias[col] : 0.0f;
  }
#pragma unroll
  for (int fr = 0; fr < 4; ++fr)
#pragma unroll
    for (int i = 0; i < 4; ++i) {
      const int row = bm + fr * 16 + (lane >> 4) * 4 + i;
      if (row >= M) continue;
#pragma unroll
      for (int fc = 0; fc < FC; ++fc) {
        const int col = colbase + fc * 16 + rsel;
        if (col < N) C[(size_t)row * N + col] = acc[fr][fc][i] + bs_[fc];
      }
    }
}

// ---------------------------------------------------------------------------
// Sampling over fp16 value. One block per (b,q); 3 fl-rows per block.
// Phase 1 (threads 0..143): per (fl,h,l,p) softmax weight + 4 tap
//   byte-offsets/weights -> LDS.  Phase 2 (8 heads x 32 dims): pure gather.
// value: [BS, LEN_IN, 256] fp16 (512 B per position).
// ---------------------------------------------------------------------------
__global__ __launch_bounds__(256) void sample3_kernel(
    const _Float16* __restrict__ value, const float* __restrict__ refpts,
    const float* __restrict__ offs_attn, _Float16* __restrict__ out_mid) {
  __shared__ int4   s_off[144];
  __shared__ float4 s_w[144];

  const int bq = blockIdx.x;       // b*900 + q
  const int b = bq / NQ;
  const int tid = threadIdx.x;

  if (tid < 144) {
    const int fl = tid / 48;
    const int rem = tid - fl * 48;  // h*6 + j
    const int h = rem / 6;
    const int j = rem - h * 6;
    const int l = j >> 1;

    const int LVL_W[3] = {100, 50, 25};
    const int LVL_BASE[3] = {0, 10000, 12500};
    const int W = LVL_W[l];
    const int base = LVL_BASE[l];
    const float fW = (float)W, fH = (float)W;  // square levels

    const int row = bq * 3 + fl;
    const float* oa = offs_attn + (size_t)row * NCAT;

    float aw[6];
    float mx = -INFINITY;
#pragma unroll
    for (int jj = 0; jj < 6; ++jj) {
      aw[jj] = oa[96 + h * 6 + jj];
      mx = fmaxf(mx, aw[jj]);
    }
    float ssum = 0.f;
#pragma unroll
    for (int jj = 0; jj < 6; ++jj) ssum += expf(aw[jj] - mx);
    const float wa = expf(aw[j] - mx) / ssum;

    const float rx = refpts[(size_t)row * 2 + 0];
    const float ry = refpts[(size_t)row * 2 + 1];
    const float ox = oa[h * 12 + j * 2 + 0];
    const float oy = oa[h * 12 + j * 2 + 1];
    const float x = (rx + ox / fW) * fW - 0.5f;
    const float y = (ry + oy / fH) * fH - 0.5f;
    const float x0 = floorf(x);
    const float y0 = floorf(y);

    int offv[4];
    float wv[4];
#pragma unroll
    for (int dy = 0; dy < 2; ++dy)
#pragma unroll
      for (int dx = 0; dx < 2; ++dx) {
        const float xi = x0 + (float)dx;
        const float yi = y0 + (float)dy;
        const float wgt = (1.0f - fabsf(x - xi)) * (1.0f - fabsf(y - yi));
        const bool valid = (xi >= 0.f) && (xi <= fW - 1.f) &&
                           (yi >= 0.f) && (yi <= fH - 1.f);
        const int xic = (int)fminf(fmaxf(xi, 0.f), fW - 1.f);
        const int yic = (int)fminf(fmaxf(yi, 0.f), fH - 1.f);
        const int pos = base + yic * W + xic;
        offv[dy * 2 + dx] = pos * 512;       // byte offset (fp16 row = 512 B)
        wv[dy * 2 + dx] = valid ? wgt * wa : 0.0f;
      }
    s_off[tid] = make_int4(offv[0], offv[1], offv[2], offv[3]);
    s_w[tid] = make_float4(wv[0], wv[1], wv[2], wv[3]);
  }
  __syncthreads();

  const int h = tid >> 5;
  const int d = tid & 31;
  const char* vb = (const char*)value +
                   ((size_t)b * LEN_IN * 256 + h * 32 + d) * 2;

#pragma unroll
  for (int fl = 0; fl < 3; ++fl) {
    float acc = 0.f;
#pragma unroll
    for (int j = 0; j < 6; ++j) {
      const int rec = fl * 48 + h * 6 + j;
      const int4 o = s_off[rec];
      const float4 w = s_w[rec];
      acc = fmaf(w.x, (float)*(const _Float16*)(vb + o.x), acc);
      acc = fmaf(w.y, (float)*(const _Float16*)(vb + o.y), acc);
      acc = fmaf(w.z, (float)*(const _Float16*)(vb + o.z), acc);
      acc = fmaf(w.w, (float)*(const _Float16*)(vb + o.w), acc);
    }
    out_mid[((size_t)bq * 3 + fl) * 256 + tid] = (_Float16)acc;
  }
}

// ---------------------------------------------------------------------------
extern "C" void kernel_launch(void* const* d_in, const int* in_sizes, int n_in,
                              void* d_out, int out_size, void* d_ws,
                              size_t ws_size, hipStream_t stream) {
  const float* query   = (const float*)d_in[0];   // [16,900,3,256]
  const float* refpts  = (const float*)d_in[1];   // [16,900,3,2]
  const float* in_flat = (const float*)d_in[2];   // [16,13125,256]
  // d_in[3]: spatial shapes (static, hardcoded)
  const float* W_value = (const float*)d_in[4];
  const float* b_value = (const float*)d_in[5];
  const float* W_off   = (const float*)d_in[6];
  const float* b_off   = (const float*)d_in[7];
  const float* W_attn  = (const float*)d_in[8];
  const float* b_attn  = (const float*)d_in[9];
  const float* W_out   = (const float*)d_in[10];
  const float* b_out   = (const float*)d_in[11];
  float* out = (float*)d_out;

  char* ws = (char*)d_ws;
  _Float16* value_h  = (_Float16*)ws; ws += (size_t)M_V * 256 * sizeof(_Float16);
  _Float16* out_mid  = (_Float16*)ws; ws += (size_t)M_Q * 256 * sizeof(_Float16);
  float* offs_attn   = (float*)ws;    ws += (size_t)M_Q * NCAT * sizeof(float);
  _Float16* Wvh = (_Float16*)ws; ws += 256 * 256 * sizeof(_Float16);
  _Float16* Wvl = (_Float16*)ws; ws += 256 * 256 * sizeof(_Float16);
  _Float16* Woh = (_Float16*)ws; ws += 256 * 256 * sizeof(_Float16);
  _Float16* Wol = (_Float16*)ws; ws += 256 * 256 * sizeof(_Float16);
  _Float16* Wch = (_Float16*)ws; ws += NCATP * 256 * sizeof(_Float16);
  _Float16* Wcl = (_Float16*)ws; ws += NCATP * 256 * sizeof(_Float16);
  float* bcat   = (float*)ws;    ws += 256 * sizeof(float);

  const dim3 blk(256);

  // ---- weight prep (tiny) ----
  convert_weight_kernel<<<dim3(256), blk, 0, stream>>>(W_value, Wvh, Wvl, 256, 256);
  convert_weight_kernel<<<dim3(256), blk, 0, stream>>>(W_out,   Woh, Wol, 256, 256);
  convert_cat_kernel<<<dim3(NCATP), blk, 0, stream>>>(W_off, W_attn, b_off, b_attn,
                                                      Wch, Wcl, bcat);

  // 1) value(fp16) = input_flatten @ W_value + b_value   (210000 x 256 x 256)
  gemm4_kernel<2, 1, _Float16><<<dim3(2, (M_V + 63) / 64), blk, 0, stream>>>(
      in_flat, Wvh, Wvl, b_value, value_h, M_V, 256);

  // 2) [offsets | attn logits] = query @ Wcat + bcat   (43200 x 144 x 256)
  gemm4_kernel<2, 2, float><<<dim3(2, (M_Q + 63) / 64), blk, 0, stream>>>(
      query, Wch, Wcl, bcat, offs_attn, M_Q, NCAT);

  // 3) softmax + bilinear sampling + weighted sum -> out_mid (fp16)
  sample3_kernel<<<dim3(BS * NQ), blk, 0, stream>>>(value_h, refpts, offs_attn,
                                                    out_mid);

  // 4) out = out_mid @ W_out + b_out   (43200 x 256 x 256), 2-term MFMA
  gemm5_kernel<2><<<dim3(2, (M_Q + 63) / 64), blk, 0, stream>>>(
      out_mid, Woh, Wol, b_out, out, M_Q, 256);
}